// Round 13
// baseline (181.886 us; speedup 1.0000x reference)
//
#include <hip/hip_runtime.h>
#include <math.h>

#define NF 4096   // ifft length (dot axis)
#define NC 256    // scan axis length
#define NJ 512    // fft output length
#define CH 128    // gram m-chunk size
#define TWO_PI_F 6.28318530717958647692f

__device__ __forceinline__ float2 cmul(float2 a, float2 b) {
    return make_float2(a.x*b.x - a.y*b.y, a.x*b.y + a.y*b.x);
}

// ---------- register DFT primitives (verified with delta inputs) ----------
__device__ __forceinline__ void dft4i(float2& x0, float2& x1, float2& x2, float2& x3, float sgn) {
    float2 t0 = make_float2(x0.x + x2.x, x0.y + x2.y);
    float2 t1 = make_float2(x0.x - x2.x, x0.y - x2.y);
    float2 t2 = make_float2(x1.x + x3.x, x1.y + x3.y);
    float2 t3 = make_float2(x1.x - x3.x, x1.y - x3.y);
    float2 it3 = make_float2(-sgn * t3.y, sgn * t3.x);   // sgn*i*t3
    x0 = make_float2(t0.x + t2.x, t0.y + t2.y);
    x2 = make_float2(t0.x - t2.x, t0.y - t2.y);
    x1 = make_float2(t1.x + it3.x, t1.y + it3.y);
    x3 = make_float2(t1.x - it3.x, t1.y - it3.y);
}

// natural-order DFT16 in registers; v_j ends up in slot 4*(j&3) + (j>>2)
__device__ __forceinline__ void dft16(float2* u, float sgn) {
    dft4i(u[0], u[4], u[8],  u[12], sgn);
    dft4i(u[1], u[5], u[9],  u[13], sgn);
    dft4i(u[2], u[6], u[10], u[14], sgn);
    dft4i(u[3], u[7], u[11], u[15], sgn);
    const float C1 = 0.9238795325112867f, S1 = 0.3826834323650898f, R2 = 0.7071067811865476f;
    u[5]  = cmul(u[5],  make_float2(C1,  sgn * S1));
    u[6]  = cmul(u[6],  make_float2(R2,  sgn * R2));
    u[7]  = cmul(u[7],  make_float2(S1,  sgn * C1));
    u[9]  = cmul(u[9],  make_float2(R2,  sgn * R2));
    u[10] = cmul(u[10], make_float2(0.f, sgn));
    u[11] = cmul(u[11], make_float2(-R2, sgn * R2));
    u[13] = cmul(u[13], make_float2(S1,  sgn * C1));
    u[14] = cmul(u[14], make_float2(-R2, sgn * R2));
    u[15] = cmul(u[15], make_float2(-C1, -sgn * S1));
    dft4i(u[0],  u[1],  u[2],  u[3],  sgn);
    dft4i(u[4],  u[5],  u[6],  u[7],  sgn);
    dft4i(u[8],  u[9],  u[10], u[11], sgn);
    dft4i(u[12], u[13], u[14], u[15], sgn);
}

// natural-order DFT8: out v[0..7] from in u[0..7]
__device__ __forceinline__ void dft8(const float2* u, float2* v, float sgn) {
    float2 e0 = u[0], e1 = u[2], e2 = u[4], e3 = u[6];
    float2 o0 = u[1], o1 = u[3], o2 = u[5], o3 = u[7];
    dft4i(e0, e1, e2, e3, sgn);
    dft4i(o0, o1, o2, o3, sgn);
    const float R2 = 0.7071067811865476f;
    float2 w1 = make_float2(R2, sgn * R2);
    float2 w2 = make_float2(0.f, sgn);
    float2 w3 = make_float2(-R2, sgn * R2);
    float2 t1 = cmul(o1, w1), t2 = cmul(o2, w2), t3 = cmul(o3, w3);
    v[0] = make_float2(e0.x + o0.x, e0.y + o0.y);
    v[4] = make_float2(e0.x - o0.x, e0.y - o0.y);
    v[1] = make_float2(e1.x + t1.x, e1.y + t1.y);
    v[5] = make_float2(e1.x - t1.x, e1.y - t1.y);
    v[2] = make_float2(e2.x + t2.x, e2.y + t2.y);
    v[6] = make_float2(e2.x - t2.x, e2.y - t2.y);
    v[3] = make_float2(e3.x + t3.x, e3.y + t3.y);
    v[7] = make_float2(e3.x - t3.x, e3.y - t3.y);
}

// ---------------- stage A: transpose x[b,f,c] -> fin[b,c,f] (scaled), 64x64 LDS tiles ----------------
__global__ __launch_bounds__(256) void transpose_kernel(const float* __restrict__ xr,
                                                        const float* __restrict__ xi,
                                                        float2* __restrict__ fin,
                                                        int b0, int nbm1, int nbshift) {
    __shared__ float ldr[64][65];   // odd word stride -> conflict-free both phases
    __shared__ float ldi[64][65];
    int wg = blockIdx.x;
    int bl = wg & nbm1;
    int rest = wg >> nbshift;
    int ft = rest & 63;            // 64 f-tiles
    int ct = rest >> 6;            // 4 c-tiles
    int f0 = ft << 6, c0 = ct << 6;
    int t = threadIdx.x;
    int cl = t & 63;
    int rq = t >> 6;               // 0..3
    const float scale = 1.0f / (4096.0f * 1.5f);
    int bg = b0 + bl;
    const float* xrb = xr + (size_t)bg * NF * NC;
    const float* xib = xi + (size_t)bg * NF * NC;
#pragma unroll
    for (int q = 0; q < 16; q++) {
        int r = q * 4 + rq;        // f-row in tile
        size_t idx = (size_t)(f0 + r) * NC + c0 + cl;   // consecutive cl -> coalesced
        ldr[cl][r] = xrb[idx] * scale;
        ldi[cl][r] = xib[idx] * scale;
    }
    __syncthreads();
    int fl = t & 63;
#pragma unroll
    for (int q = 0; q < 16; q++) {
        int cr = q * 4 + rq;       // c-row in tile
        fin[((size_t)(bl * NC + c0 + cr)) * NF + f0 + fl] =
            make_float2(ldr[cr][fl], ldi[cr][fl]);      // consecutive fl -> coalesced
    }
}

// ---------------- stage B: IFFT-4096 in place over fin[b,c,:], Stockham radix-16 ----------------
#define IPAD(a) ((a) + ((a) >> 4))

template<int P>
__device__ __forceinline__ void pass16(float2* S, int t, float sgn) {
    const int k = t & (P - 1);
    float2 u[16];
#pragma unroll
    for (int r = 0; r < 16; r++) u[r] = S[IPAD(t + 256 * r)];
    __syncthreads();
    if (P > 1) {
        float ab = sgn * (TWO_PI_F / (16.0f * (float)P)) * (float)k;
#pragma unroll
        for (int r = 1; r < 16; r++) {
            float sn, cs; __sincosf(ab * (float)r, &sn, &cs);
            u[r] = cmul(u[r], make_float2(cs, sn));
        }
    }
    dft16(u, sgn);
    const int base = 16 * P * (t / P) + k;
#pragma unroll
    for (int j = 0; j < 16; j++) {
        const int sl = ((j & 3) << 2) | (j >> 2);
        S[IPAD(base + j * P)] = u[sl];
    }
    __syncthreads();
}

__global__ __launch_bounds__(256) void ifft4096_kernel(float2* __restrict__ fin,
                                                       int bmask, int bshift) {
    __shared__ float2 S[4352];   // 34 KiB
    int wg = blockIdx.x;
    int bl = wg & bmask;
    int c = wg >> bshift;
    int t = threadIdx.x;
    size_t base = ((size_t)(bl * NC + c)) * NF;
    const float4* g4 = (const float4*)(fin + base);   // 16B-aligned (base multiple of 4096)
#pragma unroll
    for (int q = 0; q < 8; q++) {
        float4 v = g4[t + 256 * q];                   // coalesced 16B/lane
        int f = 2 * (t + 256 * q);
        S[IPAD(f)]     = make_float2(v.x, v.y);
        S[IPAD(f + 1)] = make_float2(v.z, v.w);
    }
    __syncthreads();
    pass16<1>(S, t, 1.0f);
    pass16<16>(S, t, 1.0f);
    pass16<256>(S, t, 1.0f);
    float4* o4 = (float4*)(fin + base);
#pragma unroll
    for (int q = 0; q < 8; q++) {
        int f = 2 * (t + 256 * q);
        float2 a = S[IPAD(f)];
        float2 b = S[IPAD(f + 1)];
        o4[t + 256 * q] = make_float4(a.x, a.y, b.x, b.y);
    }
}

// ---------------- stage C1: banded Gram, b128-LDS + fp64 accumulation ----------------
// WG = (bl, ks: 32-k tile, ch: 128-m chunk). 40 rows (32 + 8 halo) in interleaved-complex
// LDS, row stride 142 float2, per-sg block at 18*sg (16B-aligned; row-stride 284 words
// = 28 mod 32 -> 8 bank-groups x 8 lanes = b128 floor). Thread (kk, sg) owns all 8 d
// for k = k0+kk over m = 16*sg + mm (mm 0..15): 72 b128 reads feed 1024 f64 FMA lanes.
// fp64 accumulation: association change vs round-12 is ~1e-15 relative (chaos-safe).
#define GST 142
__global__ __launch_bounds__(256) void gram_kernel(const float2* __restrict__ fin,
                                                   float2* __restrict__ gpart) {
    __shared__ float2 lfc[40 * GST];   // 44.4 KiB
    int wg = blockIdx.x;            // ((bl*8)+ks)*32 + ch
    int bl = wg >> 8;
    int ks = (wg >> 5) & 7;
    int ch = wg & 31;
    int m0 = ch * CH;
    int k0 = ks * 32;
    int t = threadIdx.x;
    // bulk load: 40 rows x 128 float2, coalesced; store at row*GST + 18*(m>>4) + (m&15)
#pragma unroll
    for (int q = 0; q < 20; q++) {
        int e = t + 256 * q;
        int row = e >> 7;
        int m = e & 127;
        int gk = k0 - 8 + row;
        float2 v = (gk >= 0) ? fin[((size_t)(bl * NC + gk)) * NF + m0 + m]
                             : make_float2(0.f, 0.f);
        lfc[row * GST + 18 * (m >> 4) + (m & 15)] = v;
    }
    __syncthreads();
    int kk = t >> 3;                // 0..31
    int sg = t & 7;                 // 0..7
    double accx[8], accy[8];
#pragma unroll
    for (int d = 0; d < 8; d++) { accx[d] = 0.0; accy[d] = 0.0; }
    const float2* bbase = &lfc[(kk + 8) * GST + 18 * sg];
    const float2* abase = &lfc[kk * GST + 18 * sg];
#pragma unroll
    for (int mm = 0; mm < 16; mm += 2) {
        float4 bb = *(const float4*)(bbase + mm);    // complex m=16sg+mm, 16sg+mm+1
#pragma unroll
        for (int d = 1; d <= 8; d++) {
            float4 aa = *(const float4*)(abase + (8 - d) * GST + mm);
            accx[d - 1] = fma((double)aa.y, (double)bb.y,
                          fma((double)aa.x, (double)bb.x, accx[d - 1]));
            accy[d - 1] = fma((double)aa.x, (double)bb.y,
                          fma(-(double)aa.y, (double)bb.x, accy[d - 1]));
            accx[d - 1] = fma((double)aa.w, (double)bb.w,
                          fma((double)aa.z, (double)bb.z, accx[d - 1]));
            accy[d - 1] = fma((double)aa.z, (double)bb.w,
                          fma(-(double)aa.w, (double)bb.z, accy[d - 1]));
        }
    }
    // reduce over the 8 sg strips (lanes t^1, t^2, t^4 share kk)
    size_t gbase = ((size_t)(bl * 32 + ch) * NC + (k0 + kk)) * 8;
#pragma unroll
    for (int d = 0; d < 8; d++) {
        double sx = accx[d], sy = accy[d];
#pragma unroll
        for (int off = 1; off <= 4; off <<= 1) {
            sx += __shfl_xor(sx, off);
            sy += __shfl_xor(sy, off);
        }
        if (sg == 0)   // d>k entries stay exact zeros -> no poison downstream
            gpart[gbase + d] = make_float2((float)sx, (float)sy);
    }
}

// ---------------- stage C2a: sum Gram partials over 32 chunks ----------------
__global__ void gsum_kernel(const float2* __restrict__ gpart, float2* __restrict__ gs, int total) {
    int e = blockIdx.x * blockDim.x + threadIdx.x;
    if (e >= total) return;
    int bl = e >> 11;
    int kd = e & 2047;
    float2 s = make_float2(0.f, 0.f);
    for (int ch = 0; ch < 32; ch++) {
        float2 v = gpart[((size_t)(bl * 32 + ch)) * 2048 + kd];
        s.x += v.x; s.y += v.y;
    }
    gs[e] = s;
}

// ---------------- stage C2b: scalar phase recurrence, sched_barrier-pinned prefetch ----------------
#define SCAN_STEP(A0, A1, A2, A3, KIDX)  do {                                  \
    float rx0 = p1.x*A0.x - p1.y*A0.y, ry0 = p1.x*A0.y + p1.y*A0.x;            \
    float rx1 = p2.x*A0.z - p2.y*A0.w, ry1 = p2.x*A0.w + p2.y*A0.z;            \
    float rx2 = p3.x*A1.x - p3.y*A1.y, ry2 = p3.x*A1.y + p3.y*A1.x;            \
    float rx3 = p4.x*A1.z - p4.y*A1.w, ry3 = p4.x*A1.w + p4.y*A1.z;            \
    float rx4 = p5.x*A2.x - p5.y*A2.y, ry4 = p5.x*A2.y + p5.y*A2.x;            \
    float rx5 = p6.x*A2.z - p6.y*A2.w, ry5 = p6.x*A2.w + p6.y*A2.z;            \
    float rx6 = p7.x*A3.x - p7.y*A3.y, ry6 = p7.x*A3.y + p7.y*A3.x;            \
    float rx7 = p8.x*A3.z - p8.y*A3.w, ry7 = p8.x*A3.w + p8.y*A3.z;            \
    float sx = ((rx0 + rx1) + (rx2 + rx3)) + ((rx4 + rx5) + (rx6 + rx7));      \
    float sy = ((ry0 + ry1) + (ry2 + ry3)) + ((ry4 + ry5) + (ry6 + ry7));      \
    float inv = rsqrtf(sx * sx + sy * sy);                                     \
    float2 np = make_float2(sx * inv, sy * inv);                               \
    phase[t * NC + (KIDX)] = np;                                               \
    p8 = p7; p7 = p6; p6 = p5; p5 = p4; p4 = p3; p3 = p2; p2 = p1; p1 = np;    \
} while (0)

#define SCAN_LOADG4(BUF, KBASE)  do {                                          \
    _Pragma("unroll") for (int j = 0; j < 4; j++) {                            \
        _Pragma("unroll") for (int q = 0; q < 4; q++)                          \
            BUF[j][q] = gb4[((KBASE) + j) * 4 + q];                            \
    }                                                                          \
} while (0)

#define SCAN_GRP4(BUF, KBASE, FIRST)  do {                                     \
    _Pragma("unroll") for (int j = 0; j < 4; j++) {                            \
        if (FIRST && j == 0) {                                                 \
            phase[t * NC] = make_float2(1.f, 0.f);                             \
        } else {                                                               \
            SCAN_STEP(BUF[j][0], BUF[j][1], BUF[j][2], BUF[j][3], (KBASE) + j);\
        }                                                                      \
    }                                                                          \
} while (0)

__global__ __launch_bounds__(64, 1) void scan_copy_kernel(const float2* __restrict__ gs,
                                                          float2* __restrict__ phase, int nb,
                                                          const float4* __restrict__ csrc,
                                                          float4* __restrict__ cdst, int cn4) {
    if (blockIdx.x != 0) {
        int i = (blockIdx.x - 1) * 64 + threadIdx.x;
        int stride = (gridDim.x - 1) * 64;
        for (; i < cn4; i += stride) cdst[i] = csrc[i];
        return;
    }
    int t = threadIdx.x;
    if (t >= nb) return;
    const float4* gb4 = (const float4*)(gs + (size_t)t * 2048);   // 256 rows x 4 float4
    float2 z = make_float2(0.f, 0.f);
    float2 p1 = make_float2(1.f, 0.f);
    float2 p2 = z, p3 = z, p4 = z, p5 = z, p6 = z, p7 = z, p8 = z;
    float4 GA[4][4], GB[4][4];
    SCAN_LOADG4(GA, 0);
    for (int g2 = 0; g2 < 32; g2++) {
        int k0 = g2 * 8;
        SCAN_LOADG4(GB, k0 + 4);
        __builtin_amdgcn_sched_barrier(0);   // pin GB loads before GA compute
        if (g2 == 0) { SCAN_GRP4(GA, k0, true); } else { SCAN_GRP4(GA, k0, false); }
        if (g2 < 31) SCAN_LOADG4(GA, k0 + 8);
        __builtin_amdgcn_sched_barrier(0);   // pin GA-next loads before GB compute
        SCAN_GRP4(GB, k0 + 4, false);
    }
}

// ---------------- stage C3 (fallback paths only): fin *= conj(phase) ----------------
__global__ void scale_kernel(float4* __restrict__ fin4, const float2* __restrict__ phase, int n4) {
    int i = blockIdx.x * blockDim.x + threadIdx.x;
    if (i >= n4) return;
    int row = i >> 11;
    float2 ph = phase[row];
    float4 v = fin4[i];
    fin4[i] = make_float4(v.x*ph.x + v.y*ph.y, v.y*ph.x - v.x*ph.y,
                          v.z*ph.x + v.w*ph.y, v.w*ph.x - v.z*ph.y);
}

// ---------------- stage D: FFT-512 over c (zero-padded), Stockham radix-8, fused conj(phase) ----------------
#define FPAD 516   // row stride (float2) for [8][516] LDS

template<int P, bool ZTOP>
__device__ __forceinline__ void pass8x(float2* L, int fp, int i2, float sgn) {
    const int ia = i2, ib = i2 + 32;
    const int ka = ia & (P - 1), kb = ib & (P - 1);
    float2 ua[8], ub[8];
#pragma unroll
    for (int r = 0; r < 8; r++) {
        if (ZTOP && r >= 4) {
            ua[r] = make_float2(0.f, 0.f);
            ub[r] = make_float2(0.f, 0.f);
        } else {
            ua[r] = L[fp * FPAD + ia + 64 * r];
            ub[r] = L[fp * FPAD + ib + 64 * r];
        }
    }
    __syncthreads();
    if (P > 1) {
        float aba = sgn * (TWO_PI_F / (8.0f * (float)P)) * (float)ka;
        float abb = sgn * (TWO_PI_F / (8.0f * (float)P)) * (float)kb;
#pragma unroll
        for (int r = 1; r < 8; r++) {
            float sn, cs;
            __sincosf(aba * (float)r, &sn, &cs);
            ua[r] = cmul(ua[r], make_float2(cs, sn));
            __sincosf(abb * (float)r, &sn, &cs);
            ub[r] = cmul(ub[r], make_float2(cs, sn));
        }
    }
    float2 va[8], vb[8];
    dft8(ua, va, sgn);
    dft8(ub, vb, sgn);
    const int basea = 8 * P * (ia / P) + ka;
    const int baseb = 8 * P * (ib / P) + kb;
#pragma unroll
    for (int r = 0; r < 8; r++) {
        L[fp * FPAD + basea + r * P] = va[r];
        L[fp * FPAD + baseb + r * P] = vb[r];
    }
    __syncthreads();
}

__global__ __launch_bounds__(256) void fft512_kernel(const float2* __restrict__ fin,
                                                     const float2* __restrict__ ph,   // may be null
                                                     float* __restrict__ outr,
                                                     float2* __restrict__ outc,
                                                     int b0, int realOnly) {
    __shared__ float2 L[8 * FPAD];   // 33 KiB
    int wg = blockIdx.x;             // bl*512 + ftile
    int bl = wg >> 9;
    int f0 = (wg & 511) * 8;
    int t = threadIdx.x;
    int fpp = t & 7;
    int cg = t >> 3;                 // 0..31
#pragma unroll
    for (int it = 0; it < 8; it++) {
        int c = it * 32 + cg;
        float2 v = fin[((size_t)(bl * NC + c)) * NF + f0 + fpp];
        if (ph) {
            float2 p = ph[bl * NC + c];
            v = make_float2(v.x * p.x + v.y * p.y, v.y * p.x - v.x * p.y);  // f*conj(ph)
        }
        L[fpp * FPAD + c] = v;
    }
    __syncthreads();
    int fp = t & 7;
    int i2 = t >> 3;                 // 0..31
    pass8x<1, true >(L, fp, i2, -1.0f);
    pass8x<8, false>(L, fp, i2, -1.0f);
    pass8x<64, false>(L, fp, i2, -1.0f);
    size_t ob = ((size_t)((b0 + bl) * NF + f0)) * NJ;
    if (realOnly) {
#pragma unroll
        for (int fp2 = 0; fp2 < 8; fp2++)
#pragma unroll
            for (int jq = 0; jq < 2; jq++) {
                int j = t + 256 * jq;
                outr[ob + (size_t)fp2 * NJ + j] = L[fp2 * FPAD + j].x;
            }
    } else {
#pragma unroll
        for (int fp2 = 0; fp2 < 8; fp2++)
#pragma unroll
            for (int jq = 0; jq < 2; jq++) {
                int j = t + 256 * jq;
                outc[ob + (size_t)fp2 * NJ + j] = L[fp2 * FPAD + j];
            }
    }
}

// ---------------- output 0 writers (fallback paths) ----------------
__global__ void copy_kernel(const float4* __restrict__ src, float4* __restrict__ dst, int n4) {
    int i = blockIdx.x * blockDim.x + threadIdx.x;
    int stride = gridDim.x * blockDim.x;
    for (; i < n4; i += stride) dst[i] = src[i];
}
__global__ void pack_x_kernel(const float2* __restrict__ xr, const float2* __restrict__ xi,
                              float4* __restrict__ out, int n4) {
    int i = blockIdx.x * blockDim.x + threadIdx.x;
    int stride = gridDim.x * blockDim.x;
    for (; i < n4; i += stride) {
        float2 r = xr[i], m = xi[i];
        out[i] = make_float4(r.x, m.x, r.y, m.y);
    }
}

extern "C" void kernel_launch(void* const* d_in, const int* in_sizes, int n_in,
                              void* d_out, int out_size, void* d_ws, size_t ws_size,
                              hipStream_t stream) {
    const float* xr = (const float*)d_in[0];
    const float* xi = (const float*)d_in[1];
    float* out = (float*)d_out;

    if (out_size < 40000000) {
        // real-only outputs: out0 = x_real (8388608 f), out3 = Re(out3) (16777216 f)
        float* out0r = out;
        float* out3r = out + 8388608;
        size_t need = (size_t)(8388608 + 524288 + 16384 + 2048) * sizeof(float2);
        if (ws_size >= need) {
            float2* fin   = (float2*)d_ws;
            float2* gpart = fin + 8388608;
            float2* gsb   = gpart + 524288;
            float2* phase = gsb + 16384;
            transpose_kernel<<<8 * 256, 256, 0, stream>>>(xr, xi, fin, 0, 7, 3);
            ifft4096_kernel<<<8 * NC, 256, 0, stream>>>(fin, 7, 3);
            gram_kernel<<<8 * 256, 256, 0, stream>>>(fin, gpart);
            gsum_kernel<<<(8 * 2048) / 256, 256, 0, stream>>>(gpart, gsb, 8 * 2048);
            // block 0: serial scan; blocks 1..2048: out0 copy (independent, overlapped)
            scan_copy_kernel<<<2049, 64, 0, stream>>>(gsb, phase, 8,
                                                      (const float4*)xr, (float4*)out0r, 2097152);
            fft512_kernel<<<8 * 512, 256, 0, stream>>>(fin, phase, out3r, nullptr, 0, 1);
        } else {
            // two batch-half passes; fin in out0 region; gram scratch in out3 tail
            float2* fin   = (float2*)out0r;
            float2* o3f2  = (float2*)out3r;
            float2* gpart = o3f2 + (8388608 - 262144 - 8192 - 1024);
            float2* gsb   = o3f2 + (8388608 - 8192 - 1024);
            float2* phase = o3f2 + (8388608 - 1024);
            for (int p = 0; p < 2; p++) {
                int b0 = p * 4;
                transpose_kernel<<<4 * 256, 256, 0, stream>>>(xr, xi, fin, b0, 3, 2);
                ifft4096_kernel<<<4 * NC, 256, 0, stream>>>(fin, 3, 2);
                gram_kernel<<<4 * 256, 256, 0, stream>>>(fin, gpart);
                gsum_kernel<<<(4 * 2048) / 256, 256, 0, stream>>>(gpart, gsb, 4 * 2048);
                scan_copy_kernel<<<1, 64, 0, stream>>>(gsb, phase, 4, nullptr, nullptr, 0);
                scale_kernel<<<4 * 2048, 256, 0, stream>>>((float4*)fin, phase, 4 * 524288);
                fft512_kernel<<<4 * 512, 256, 0, stream>>>(fin, nullptr, out3r, nullptr, b0, 1);
            }
            copy_kernel<<<2048, 256, 0, stream>>>((const float4*)xr, (float4*)out0r, 2097152);
        }
    } else {
        // defensive path: complex outputs as float pairs
        float2* out0f2 = (float2*)out;
        float2* out3f2 = (float2*)(out + 16777216);
        float2* fin   = out0f2;
        float2* gpart = out3f2 + (16777216 - 524288 - 16384 - 2048);
        float2* gsb   = out3f2 + (16777216 - 16384 - 2048);
        float2* phase = out3f2 + (16777216 - 2048);
        transpose_kernel<<<8 * 256, 256, 0, stream>>>(xr, xi, fin, 0, 7, 3);
        ifft4096_kernel<<<8 * NC, 256, 0, stream>>>(fin, 7, 3);
        gram_kernel<<<8 * 256, 256, 0, stream>>>(fin, gpart);
        gsum_kernel<<<(8 * 2048) / 256, 256, 0, stream>>>(gpart, gsb, 8 * 2048);
        scan_copy_kernel<<<1, 64, 0, stream>>>(gsb, phase, 8, nullptr, nullptr, 0);
        scale_kernel<<<8 * 2048, 256, 0, stream>>>((float4*)fin, phase, 8 * 524288);
        fft512_kernel<<<8 * 512, 256, 0, stream>>>(fin, nullptr, nullptr, out3f2, 0, 0);
        pack_x_kernel<<<4096, 256, 0, stream>>>((const float2*)xr, (const float2*)xi,
                                                (float4*)out0f2, 4194304);
    }
}

// Round 14
// 181.759 us; speedup vs baseline: 1.0007x; 1.0007x over previous
//
#include <hip/hip_runtime.h>
#include <math.h>

#define NF 4096   // ifft length (dot axis)
#define NC 256    // scan axis length
#define NJ 512    // fft output length
#define CH 128    // gram m-chunk size
#define TWO_PI_F 6.28318530717958647692f

__device__ __forceinline__ float2 cmul(float2 a, float2 b) {
    return make_float2(a.x*b.x - a.y*b.y, a.x*b.y + a.y*b.x);
}

// ---------- register DFT primitives (verified with delta inputs) ----------
__device__ __forceinline__ void dft4i(float2& x0, float2& x1, float2& x2, float2& x3, float sgn) {
    float2 t0 = make_float2(x0.x + x2.x, x0.y + x2.y);
    float2 t1 = make_float2(x0.x - x2.x, x0.y - x2.y);
    float2 t2 = make_float2(x1.x + x3.x, x1.y + x3.y);
    float2 t3 = make_float2(x1.x - x3.x, x1.y - x3.y);
    float2 it3 = make_float2(-sgn * t3.y, sgn * t3.x);   // sgn*i*t3
    x0 = make_float2(t0.x + t2.x, t0.y + t2.y);
    x2 = make_float2(t0.x - t2.x, t0.y - t2.y);
    x1 = make_float2(t1.x + it3.x, t1.y + it3.y);
    x3 = make_float2(t1.x - it3.x, t1.y - it3.y);
}

// natural-order DFT16 in registers; v_j ends up in slot 4*(j&3) + (j>>2)
__device__ __forceinline__ void dft16(float2* u, float sgn) {
    dft4i(u[0], u[4], u[8],  u[12], sgn);
    dft4i(u[1], u[5], u[9],  u[13], sgn);
    dft4i(u[2], u[6], u[10], u[14], sgn);
    dft4i(u[3], u[7], u[11], u[15], sgn);
    const float C1 = 0.9238795325112867f, S1 = 0.3826834323650898f, R2 = 0.7071067811865476f;
    u[5]  = cmul(u[5],  make_float2(C1,  sgn * S1));
    u[6]  = cmul(u[6],  make_float2(R2,  sgn * R2));
    u[7]  = cmul(u[7],  make_float2(S1,  sgn * C1));
    u[9]  = cmul(u[9],  make_float2(R2,  sgn * R2));
    u[10] = cmul(u[10], make_float2(0.f, sgn));
    u[11] = cmul(u[11], make_float2(-R2, sgn * R2));
    u[13] = cmul(u[13], make_float2(S1,  sgn * C1));
    u[14] = cmul(u[14], make_float2(-R2, sgn * R2));
    u[15] = cmul(u[15], make_float2(-C1, -sgn * S1));
    dft4i(u[0],  u[1],  u[2],  u[3],  sgn);
    dft4i(u[4],  u[5],  u[6],  u[7],  sgn);
    dft4i(u[8],  u[9],  u[10], u[11], sgn);
    dft4i(u[12], u[13], u[14], u[15], sgn);
}

// natural-order DFT8: out v[0..7] from in u[0..7]
__device__ __forceinline__ void dft8(const float2* u, float2* v, float sgn) {
    float2 e0 = u[0], e1 = u[2], e2 = u[4], e3 = u[6];
    float2 o0 = u[1], o1 = u[3], o2 = u[5], o3 = u[7];
    dft4i(e0, e1, e2, e3, sgn);
    dft4i(o0, o1, o2, o3, sgn);
    const float R2 = 0.7071067811865476f;
    float2 w1 = make_float2(R2, sgn * R2);
    float2 w2 = make_float2(0.f, sgn);
    float2 w3 = make_float2(-R2, sgn * R2);
    float2 t1 = cmul(o1, w1), t2 = cmul(o2, w2), t3 = cmul(o3, w3);
    v[0] = make_float2(e0.x + o0.x, e0.y + o0.y);
    v[4] = make_float2(e0.x - o0.x, e0.y - o0.y);
    v[1] = make_float2(e1.x + t1.x, e1.y + t1.y);
    v[5] = make_float2(e1.x - t1.x, e1.y - t1.y);
    v[2] = make_float2(e2.x + t2.x, e2.y + t2.y);
    v[6] = make_float2(e2.x - t2.x, e2.y - t2.y);
    v[3] = make_float2(e3.x + t3.x, e3.y + t3.y);
    v[7] = make_float2(e3.x - t3.x, e3.y - t3.y);
}

// ---------------- stage A: transpose x[b,f,c] -> fin[b,c,f] (scaled), 64x64 LDS tiles ----------------
__global__ __launch_bounds__(256) void transpose_kernel(const float* __restrict__ xr,
                                                        const float* __restrict__ xi,
                                                        float2* __restrict__ fin,
                                                        int b0, int nbm1, int nbshift) {
    __shared__ float ldr[64][65];   // odd word stride -> conflict-free both phases
    __shared__ float ldi[64][65];
    int wg = blockIdx.x;
    int bl = wg & nbm1;
    int rest = wg >> nbshift;
    int ft = rest & 63;            // 64 f-tiles
    int ct = rest >> 6;            // 4 c-tiles
    int f0 = ft << 6, c0 = ct << 6;
    int t = threadIdx.x;
    int cl = t & 63;
    int rq = t >> 6;               // 0..3
    const float scale = 1.0f / (4096.0f * 1.5f);
    int bg = b0 + bl;
    const float* xrb = xr + (size_t)bg * NF * NC;
    const float* xib = xi + (size_t)bg * NF * NC;
#pragma unroll
    for (int q = 0; q < 16; q++) {
        int r = q * 4 + rq;        // f-row in tile
        size_t idx = (size_t)(f0 + r) * NC + c0 + cl;   // consecutive cl -> coalesced
        ldr[cl][r] = xrb[idx] * scale;
        ldi[cl][r] = xib[idx] * scale;
    }
    __syncthreads();
    int fl = t & 63;
#pragma unroll
    for (int q = 0; q < 16; q++) {
        int cr = q * 4 + rq;       // c-row in tile
        fin[((size_t)(bl * NC + c0 + cr)) * NF + f0 + fl] =
            make_float2(ldr[cr][fl], ldi[cr][fl]);      // consecutive fl -> coalesced
    }
}

// ---------------- stage B: IFFT-4096 in place over fin[b,c,:], Stockham radix-16 ----------------
#define IPAD(a) ((a) + ((a) >> 4))

template<int P>
__device__ __forceinline__ void pass16(float2* S, int t, float sgn) {
    const int k = t & (P - 1);
    float2 u[16];
#pragma unroll
    for (int r = 0; r < 16; r++) u[r] = S[IPAD(t + 256 * r)];
    __syncthreads();
    if (P > 1) {
        float ab = sgn * (TWO_PI_F / (16.0f * (float)P)) * (float)k;
#pragma unroll
        for (int r = 1; r < 16; r++) {
            float sn, cs; __sincosf(ab * (float)r, &sn, &cs);
            u[r] = cmul(u[r], make_float2(cs, sn));
        }
    }
    dft16(u, sgn);
    const int base = 16 * P * (t / P) + k;
#pragma unroll
    for (int j = 0; j < 16; j++) {
        const int sl = ((j & 3) << 2) | (j >> 2);
        S[IPAD(base + j * P)] = u[sl];
    }
    __syncthreads();
}

__global__ __launch_bounds__(256) void ifft4096_kernel(float2* __restrict__ fin,
                                                       int bmask, int bshift) {
    __shared__ float2 S[4352];   // 34 KiB
    int wg = blockIdx.x;
    int bl = wg & bmask;
    int c = wg >> bshift;
    int t = threadIdx.x;
    size_t base = ((size_t)(bl * NC + c)) * NF;
    const float4* g4 = (const float4*)(fin + base);   // 16B-aligned (base multiple of 4096)
#pragma unroll
    for (int q = 0; q < 8; q++) {
        float4 v = g4[t + 256 * q];                   // coalesced 16B/lane
        int f = 2 * (t + 256 * q);
        S[IPAD(f)]     = make_float2(v.x, v.y);
        S[IPAD(f + 1)] = make_float2(v.z, v.w);
    }
    __syncthreads();
    pass16<1>(S, t, 1.0f);
    pass16<16>(S, t, 1.0f);
    pass16<256>(S, t, 1.0f);
    float4* o4 = (float4*)(fin + base);
#pragma unroll
    for (int q = 0; q < 8; q++) {
        int f = 2 * (t + 256 * q);
        float2 a = S[IPAD(f)];
        float2 b = S[IPAD(f + 1)];
        o4[t + 256 * q] = make_float4(a.x, a.y, b.x, b.y);
    }
}

// ---------------- stage C1: banded Gram, b128-LDS + fp64 accumulation ----------------
#define GST 142
__global__ __launch_bounds__(256) void gram_kernel(const float2* __restrict__ fin,
                                                   float2* __restrict__ gpart) {
    __shared__ float2 lfc[40 * GST];   // 44.4 KiB
    int wg = blockIdx.x;            // ((bl*8)+ks)*32 + ch
    int bl = wg >> 8;
    int ks = (wg >> 5) & 7;
    int ch = wg & 31;
    int m0 = ch * CH;
    int k0 = ks * 32;
    int t = threadIdx.x;
#pragma unroll
    for (int q = 0; q < 20; q++) {
        int e = t + 256 * q;
        int row = e >> 7;
        int m = e & 127;
        int gk = k0 - 8 + row;
        float2 v = (gk >= 0) ? fin[((size_t)(bl * NC + gk)) * NF + m0 + m]
                             : make_float2(0.f, 0.f);
        lfc[row * GST + 18 * (m >> 4) + (m & 15)] = v;
    }
    __syncthreads();
    int kk = t >> 3;                // 0..31
    int sg = t & 7;                 // 0..7
    double accx[8], accy[8];
#pragma unroll
    for (int d = 0; d < 8; d++) { accx[d] = 0.0; accy[d] = 0.0; }
    const float2* bbase = &lfc[(kk + 8) * GST + 18 * sg];
    const float2* abase = &lfc[kk * GST + 18 * sg];
#pragma unroll
    for (int mm = 0; mm < 16; mm += 2) {
        float4 bb = *(const float4*)(bbase + mm);    // complex m=16sg+mm, 16sg+mm+1
#pragma unroll
        for (int d = 1; d <= 8; d++) {
            float4 aa = *(const float4*)(abase + (8 - d) * GST + mm);
            accx[d - 1] = fma((double)aa.y, (double)bb.y,
                          fma((double)aa.x, (double)bb.x, accx[d - 1]));
            accy[d - 1] = fma((double)aa.x, (double)bb.y,
                          fma(-(double)aa.y, (double)bb.x, accy[d - 1]));
            accx[d - 1] = fma((double)aa.w, (double)bb.w,
                          fma((double)aa.z, (double)bb.z, accx[d - 1]));
            accy[d - 1] = fma((double)aa.z, (double)bb.w,
                          fma(-(double)aa.w, (double)bb.z, accy[d - 1]));
        }
    }
    size_t gbase = ((size_t)(bl * 32 + ch) * NC + (k0 + kk)) * 8;
#pragma unroll
    for (int d = 0; d < 8; d++) {
        double sx = accx[d], sy = accy[d];
#pragma unroll
        for (int off = 1; off <= 4; off <<= 1) {
            sx += __shfl_xor(sx, off);
            sy += __shfl_xor(sy, off);
        }
        if (sg == 0)   // d>k entries stay exact zeros -> no poison downstream
            gpart[gbase + d] = make_float2((float)sx, (float)sy);
    }
}

// ---------------- stage C2a: sum Gram partials over 32 chunks ----------------
__global__ void gsum_kernel(const float2* __restrict__ gpart, float2* __restrict__ gs, int total) {
    int e = blockIdx.x * blockDim.x + threadIdx.x;
    if (e >= total) return;
    int bl = e >> 11;
    int kd = e & 2047;
    float2 s = make_float2(0.f, 0.f);
    for (int ch = 0; ch < 32; ch++) {
        float2 v = gpart[((size_t)(bl * 32 + ch)) * 2048 + kd];
        s.x += v.x; s.y += v.y;
    }
    gs[e] = s;
}

// ---------------- stage C2b: scalar phase recurrence, deep (12-step) pinned prefetch ----------------
// Arithmetic identical to rounds 9-13 (same tree, same order). Only load scheduling changed:
// 4 rotating register buffers, loads issued 3 groups (12 k-steps ~ >900 cyc) ahead of use,
// each load block pinned with sched_barrier(0). Prefetch-tail overruns read inside d_ws only.
#define SCAN_STEP(A0, A1, A2, A3, KIDX)  do {                                  \
    float rx0 = p1.x*A0.x - p1.y*A0.y, ry0 = p1.x*A0.y + p1.y*A0.x;            \
    float rx1 = p2.x*A0.z - p2.y*A0.w, ry1 = p2.x*A0.w + p2.y*A0.z;            \
    float rx2 = p3.x*A1.x - p3.y*A1.y, ry2 = p3.x*A1.y + p3.y*A1.x;            \
    float rx3 = p4.x*A1.z - p4.y*A1.w, ry3 = p4.x*A1.w + p4.y*A1.z;            \
    float rx4 = p5.x*A2.x - p5.y*A2.y, ry4 = p5.x*A2.y + p5.y*A2.x;            \
    float rx5 = p6.x*A2.z - p6.y*A2.w, ry5 = p6.x*A2.w + p6.y*A2.z;            \
    float rx6 = p7.x*A3.x - p7.y*A3.y, ry6 = p7.x*A3.y + p7.y*A3.x;            \
    float rx7 = p8.x*A3.z - p8.y*A3.w, ry7 = p8.x*A3.w + p8.y*A3.z;            \
    float sx = ((rx0 + rx1) + (rx2 + rx3)) + ((rx4 + rx5) + (rx6 + rx7));      \
    float sy = ((ry0 + ry1) + (ry2 + ry3)) + ((ry4 + ry5) + (ry6 + ry7));      \
    float inv = rsqrtf(sx * sx + sy * sy);                                     \
    float2 np = make_float2(sx * inv, sy * inv);                               \
    phase[t * NC + (KIDX)] = np;                                               \
    p8 = p7; p7 = p6; p6 = p5; p5 = p4; p4 = p3; p3 = p2; p2 = p1; p1 = np;    \
} while (0)

#define SCAN_LOADG4(BUF, KBASE)  do {                                          \
    _Pragma("unroll") for (int j = 0; j < 4; j++) {                            \
        _Pragma("unroll") for (int q = 0; q < 4; q++)                          \
            BUF[j][q] = gb4[((KBASE) + j) * 4 + q];                            \
    }                                                                          \
} while (0)

#define SCAN_GRP4(BUF, KBASE, FIRST)  do {                                     \
    _Pragma("unroll") for (int j = 0; j < 4; j++) {                            \
        if (FIRST && j == 0) {                                                 \
            phase[t * NC] = make_float2(1.f, 0.f);                             \
        } else {                                                               \
            SCAN_STEP(BUF[j][0], BUF[j][1], BUF[j][2], BUF[j][3], (KBASE) + j);\
        }                                                                      \
    }                                                                          \
} while (0)

__global__ __launch_bounds__(64, 1) void scan_copy_kernel(const float2* __restrict__ gs,
                                                          float2* __restrict__ phase, int nb,
                                                          const float4* __restrict__ csrc,
                                                          float4* __restrict__ cdst, int cn4) {
    if (blockIdx.x != 0) {
        int i = (blockIdx.x - 1) * 64 + threadIdx.x;
        int stride = (gridDim.x - 1) * 64;
        for (; i < cn4; i += stride) cdst[i] = csrc[i];
        return;
    }
    int t = threadIdx.x;
    if (t >= nb) return;
    const float4* gb4 = (const float4*)(gs + (size_t)t * 2048);   // 256 rows x 4 float4
    float2 z = make_float2(0.f, 0.f);
    float2 p1 = make_float2(1.f, 0.f);
    float2 p2 = z, p3 = z, p4 = z, p5 = z, p6 = z, p7 = z, p8 = z;
    float4 B0[4][4], B1[4][4], B2[4][4], B3[4][4];
    SCAN_LOADG4(B0, 0);
    SCAN_LOADG4(B1, 4);
    SCAN_LOADG4(B2, 8);
    __builtin_amdgcn_sched_barrier(0);
    for (int i = 0; i < 16; i++) {
        int k0 = i * 16;
        SCAN_LOADG4(B3, k0 + 12);
        __builtin_amdgcn_sched_barrier(0);
        if (i == 0) { SCAN_GRP4(B0, k0, true); } else { SCAN_GRP4(B0, k0, false); }
        SCAN_LOADG4(B0, k0 + 16);          // prefetch-tail overrun (i=15) stays in d_ws
        __builtin_amdgcn_sched_barrier(0);
        SCAN_GRP4(B1, k0 + 4, false);
        SCAN_LOADG4(B1, k0 + 20);
        __builtin_amdgcn_sched_barrier(0);
        SCAN_GRP4(B2, k0 + 8, false);
        SCAN_LOADG4(B2, k0 + 24);
        __builtin_amdgcn_sched_barrier(0);
        SCAN_GRP4(B3, k0 + 12, false);
    }
}

// ---------------- stage C3 (fallback paths only): fin *= conj(phase) ----------------
__global__ void scale_kernel(float4* __restrict__ fin4, const float2* __restrict__ phase, int n4) {
    int i = blockIdx.x * blockDim.x + threadIdx.x;
    if (i >= n4) return;
    int row = i >> 11;
    float2 ph = phase[row];
    float4 v = fin4[i];
    fin4[i] = make_float4(v.x*ph.x + v.y*ph.y, v.y*ph.x - v.x*ph.y,
                          v.z*ph.x + v.w*ph.y, v.w*ph.x - v.z*ph.y);
}

// ---------------- stage D: FFT-512 over c (zero-padded), Stockham radix-8, fused conj(phase) ----------------
#define FPAD 516   // row stride (float2) for [8][516] LDS

template<int P, bool ZTOP>
__device__ __forceinline__ void pass8x(float2* L, int fp, int i2, float sgn) {
    const int ia = i2, ib = i2 + 32;
    const int ka = ia & (P - 1), kb = ib & (P - 1);
    float2 ua[8], ub[8];
#pragma unroll
    for (int r = 0; r < 8; r++) {
        if (ZTOP && r >= 4) {
            ua[r] = make_float2(0.f, 0.f);
            ub[r] = make_float2(0.f, 0.f);
        } else {
            ua[r] = L[fp * FPAD + ia + 64 * r];
            ub[r] = L[fp * FPAD + ib + 64 * r];
        }
    }
    __syncthreads();
    if (P > 1) {
        float aba = sgn * (TWO_PI_F / (8.0f * (float)P)) * (float)ka;
        float abb = sgn * (TWO_PI_F / (8.0f * (float)P)) * (float)kb;
#pragma unroll
        for (int r = 1; r < 8; r++) {
            float sn, cs;
            __sincosf(aba * (float)r, &sn, &cs);
            ua[r] = cmul(ua[r], make_float2(cs, sn));
            __sincosf(abb * (float)r, &sn, &cs);
            ub[r] = cmul(ub[r], make_float2(cs, sn));
        }
    }
    float2 va[8], vb[8];
    dft8(ua, va, sgn);
    dft8(ub, vb, sgn);
    const int basea = 8 * P * (ia / P) + ka;
    const int baseb = 8 * P * (ib / P) + kb;
#pragma unroll
    for (int r = 0; r < 8; r++) {
        L[fp * FPAD + basea + r * P] = va[r];
        L[fp * FPAD + baseb + r * P] = vb[r];
    }
    __syncthreads();
}

__global__ __launch_bounds__(256) void fft512_kernel(const float2* __restrict__ fin,
                                                     const float2* __restrict__ ph,   // may be null
                                                     float* __restrict__ outr,
                                                     float2* __restrict__ outc,
                                                     int b0, int realOnly) {
    __shared__ float2 L[8 * FPAD];   // 33 KiB
    int wg = blockIdx.x;             // bl*512 + ftile
    int bl = wg >> 9;
    int f0 = (wg & 511) * 8;
    int t = threadIdx.x;
    int fpp = t & 7;
    int cg = t >> 3;                 // 0..31
#pragma unroll
    for (int it = 0; it < 8; it++) {
        int c = it * 32 + cg;
        float2 v = fin[((size_t)(bl * NC + c)) * NF + f0 + fpp];
        if (ph) {
            float2 p = ph[bl * NC + c];
            v = make_float2(v.x * p.x + v.y * p.y, v.y * p.x - v.x * p.y);  // f*conj(ph)
        }
        L[fpp * FPAD + c] = v;
    }
    __syncthreads();
    int fp = t & 7;
    int i2 = t >> 3;                 // 0..31
    pass8x<1, true >(L, fp, i2, -1.0f);
    pass8x<8, false>(L, fp, i2, -1.0f);
    pass8x<64, false>(L, fp, i2, -1.0f);
    size_t ob = ((size_t)((b0 + bl) * NF + f0)) * NJ;
    if (realOnly) {
#pragma unroll
        for (int fp2 = 0; fp2 < 8; fp2++) {
            int j = 2 * t;           // thread covers j, j+1 -> 8B store, coalesced
            float2 w = make_float2(L[fp2 * FPAD + j].x, L[fp2 * FPAD + j + 1].x);
            *(float2*)&outr[ob + (size_t)fp2 * NJ + j] = w;
        }
    } else {
#pragma unroll
        for (int fp2 = 0; fp2 < 8; fp2++)
#pragma unroll
            for (int jq = 0; jq < 2; jq++) {
                int j = t + 256 * jq;
                outc[ob + (size_t)fp2 * NJ + j] = L[fp2 * FPAD + j];
            }
    }
}

// ---------------- output 0 writers (fallback paths) ----------------
__global__ void copy_kernel(const float4* __restrict__ src, float4* __restrict__ dst, int n4) {
    int i = blockIdx.x * blockDim.x + threadIdx.x;
    int stride = gridDim.x * blockDim.x;
    for (; i < n4; i += stride) dst[i] = src[i];
}
__global__ void pack_x_kernel(const float2* __restrict__ xr, const float2* __restrict__ xi,
                              float4* __restrict__ out, int n4) {
    int i = blockIdx.x * blockDim.x + threadIdx.x;
    int stride = gridDim.x * blockDim.x;
    for (; i < n4; i += stride) {
        float2 r = xr[i], m = xi[i];
        out[i] = make_float4(r.x, m.x, r.y, m.y);
    }
}

extern "C" void kernel_launch(void* const* d_in, const int* in_sizes, int n_in,
                              void* d_out, int out_size, void* d_ws, size_t ws_size,
                              hipStream_t stream) {
    const float* xr = (const float*)d_in[0];
    const float* xi = (const float*)d_in[1];
    float* out = (float*)d_out;

    if (out_size < 40000000) {
        // real-only outputs: out0 = x_real (8388608 f), out3 = Re(out3) (16777216 f)
        float* out0r = out;
        float* out3r = out + 8388608;
        size_t need = (size_t)(8388608 + 524288 + 16384 + 2048) * sizeof(float2);
        if (ws_size >= need) {
            float2* fin   = (float2*)d_ws;
            float2* gpart = fin + 8388608;
            float2* gsb   = gpart + 524288;
            float2* phase = gsb + 16384;
            transpose_kernel<<<8 * 256, 256, 0, stream>>>(xr, xi, fin, 0, 7, 3);
            ifft4096_kernel<<<8 * NC, 256, 0, stream>>>(fin, 7, 3);
            gram_kernel<<<8 * 256, 256, 0, stream>>>(fin, gpart);
            gsum_kernel<<<(8 * 2048) / 256, 256, 0, stream>>>(gpart, gsb, 8 * 2048);
            // block 0: serial scan; blocks 1..2048: out0 copy (independent, overlapped)
            scan_copy_kernel<<<2049, 64, 0, stream>>>(gsb, phase, 8,
                                                      (const float4*)xr, (float4*)out0r, 2097152);
            fft512_kernel<<<8 * 512, 256, 0, stream>>>(fin, phase, out3r, nullptr, 0, 1);
        } else {
            // two batch-half passes; fin in out0 region; gram scratch in out3 tail
            float2* fin   = (float2*)out0r;
            float2* o3f2  = (float2*)out3r;
            float2* gpart = o3f2 + (8388608 - 262144 - 8192 - 1024);
            float2* gsb   = o3f2 + (8388608 - 8192 - 1024);
            float2* phase = o3f2 + (8388608 - 1024);
            for (int p = 0; p < 2; p++) {
                int b0 = p * 4;
                transpose_kernel<<<4 * 256, 256, 0, stream>>>(xr, xi, fin, b0, 3, 2);
                ifft4096_kernel<<<4 * NC, 256, 0, stream>>>(fin, 3, 2);
                gram_kernel<<<4 * 256, 256, 0, stream>>>(fin, gpart);
                gsum_kernel<<<(4 * 2048) / 256, 256, 0, stream>>>(gpart, gsb, 4 * 2048);
                scan_copy_kernel<<<1, 64, 0, stream>>>(gsb, phase, 4, nullptr, nullptr, 0);
                scale_kernel<<<4 * 2048, 256, 0, stream>>>((float4*)fin, phase, 4 * 524288);
                fft512_kernel<<<4 * 512, 256, 0, stream>>>(fin, nullptr, out3r, nullptr, b0, 1);
            }
            copy_kernel<<<2048, 256, 0, stream>>>((const float4*)xr, (float4*)out0r, 2097152);
        }
    } else {
        // defensive path: complex outputs as float pairs
        float2* out0f2 = (float2*)out;
        float2* out3f2 = (float2*)(out + 16777216);
        float2* fin   = out0f2;
        float2* gpart = out3f2 + (16777216 - 524288 - 16384 - 2048);
        float2* gsb   = out3f2 + (16777216 - 16384 - 2048);
        float2* phase = out3f2 + (16777216 - 2048);
        transpose_kernel<<<8 * 256, 256, 0, stream>>>(xr, xi, fin, 0, 7, 3);
        ifft4096_kernel<<<8 * NC, 256, 0, stream>>>(fin, 7, 3);
        gram_kernel<<<8 * 256, 256, 0, stream>>>(fin, gpart);
        gsum_kernel<<<(8 * 2048) / 256, 256, 0, stream>>>(gpart, gsb, 8 * 2048);
        scan_copy_kernel<<<1, 64, 0, stream>>>(gsb, phase, 8, nullptr, nullptr, 0);
        scale_kernel<<<8 * 2048, 256, 0, stream>>>((float4*)fin, phase, 8 * 524288);
        fft512_kernel<<<8 * 512, 256, 0, stream>>>(fin, nullptr, nullptr, out3f2, 0, 0);
        pack_x_kernel<<<4096, 256, 0, stream>>>((const float2*)xr, (const float2*)xi,
                                                (float4*)out0f2, 4194304);
    }
}

// Round 15
// 169.269 us; speedup vs baseline: 1.0745x; 1.0738x over previous
//
#include <hip/hip_runtime.h>
#include <math.h>

#define NF 4096   // ifft length (dot axis)
#define NC 256    // scan axis length
#define NJ 512    // fft output length
#define CH 128    // gram m-chunk size
#define TWO_PI_F 6.28318530717958647692f

__device__ __forceinline__ float2 cmul(float2 a, float2 b) {
    return make_float2(a.x*b.x - a.y*b.y, a.x*b.y + a.y*b.x);
}

// ---------- register DFT primitives (verified with delta inputs) ----------
__device__ __forceinline__ void dft4i(float2& x0, float2& x1, float2& x2, float2& x3, float sgn) {
    float2 t0 = make_float2(x0.x + x2.x, x0.y + x2.y);
    float2 t1 = make_float2(x0.x - x2.x, x0.y - x2.y);
    float2 t2 = make_float2(x1.x + x3.x, x1.y + x3.y);
    float2 t3 = make_float2(x1.x - x3.x, x1.y - x3.y);
    float2 it3 = make_float2(-sgn * t3.y, sgn * t3.x);   // sgn*i*t3
    x0 = make_float2(t0.x + t2.x, t0.y + t2.y);
    x2 = make_float2(t0.x - t2.x, t0.y - t2.y);
    x1 = make_float2(t1.x + it3.x, t1.y + it3.y);
    x3 = make_float2(t1.x - it3.x, t1.y - it3.y);
}

// natural-order DFT16 in registers; v_j ends up in slot 4*(j&3) + (j>>2)
__device__ __forceinline__ void dft16(float2* u, float sgn) {
    dft4i(u[0], u[4], u[8],  u[12], sgn);
    dft4i(u[1], u[5], u[9],  u[13], sgn);
    dft4i(u[2], u[6], u[10], u[14], sgn);
    dft4i(u[3], u[7], u[11], u[15], sgn);
    const float C1 = 0.9238795325112867f, S1 = 0.3826834323650898f, R2 = 0.7071067811865476f;
    u[5]  = cmul(u[5],  make_float2(C1,  sgn * S1));
    u[6]  = cmul(u[6],  make_float2(R2,  sgn * R2));
    u[7]  = cmul(u[7],  make_float2(S1,  sgn * C1));
    u[9]  = cmul(u[9],  make_float2(R2,  sgn * R2));
    u[10] = cmul(u[10], make_float2(0.f, sgn));
    u[11] = cmul(u[11], make_float2(-R2, sgn * R2));
    u[13] = cmul(u[13], make_float2(S1,  sgn * C1));
    u[14] = cmul(u[14], make_float2(-R2, sgn * R2));
    u[15] = cmul(u[15], make_float2(-C1, -sgn * S1));
    dft4i(u[0],  u[1],  u[2],  u[3],  sgn);
    dft4i(u[4],  u[5],  u[6],  u[7],  sgn);
    dft4i(u[8],  u[9],  u[10], u[11], sgn);
    dft4i(u[12], u[13], u[14], u[15], sgn);
}

// natural-order DFT8: out v[0..7] from in u[0..7]
__device__ __forceinline__ void dft8(const float2* u, float2* v, float sgn) {
    float2 e0 = u[0], e1 = u[2], e2 = u[4], e3 = u[6];
    float2 o0 = u[1], o1 = u[3], o2 = u[5], o3 = u[7];
    dft4i(e0, e1, e2, e3, sgn);
    dft4i(o0, o1, o2, o3, sgn);
    const float R2 = 0.7071067811865476f;
    float2 w1 = make_float2(R2, sgn * R2);
    float2 w2 = make_float2(0.f, sgn);
    float2 w3 = make_float2(-R2, sgn * R2);
    float2 t1 = cmul(o1, w1), t2 = cmul(o2, w2), t3 = cmul(o3, w3);
    v[0] = make_float2(e0.x + o0.x, e0.y + o0.y);
    v[4] = make_float2(e0.x - o0.x, e0.y - o0.y);
    v[1] = make_float2(e1.x + t1.x, e1.y + t1.y);
    v[5] = make_float2(e1.x - t1.x, e1.y - t1.y);
    v[2] = make_float2(e2.x + t2.x, e2.y + t2.y);
    v[6] = make_float2(e2.x - t2.x, e2.y - t2.y);
    v[3] = make_float2(e3.x + t3.x, e3.y + t3.y);
    v[7] = make_float2(e3.x - t3.x, e3.y - t3.y);
}

// ---------------- stage A: transpose x[b,f,c] -> fin[b,c,f] (scaled), 64x64 LDS tiles ----------------
__global__ __launch_bounds__(256) void transpose_kernel(const float* __restrict__ xr,
                                                        const float* __restrict__ xi,
                                                        float2* __restrict__ fin,
                                                        int b0, int nbm1, int nbshift) {
    __shared__ float ldr[64][65];   // odd word stride -> conflict-free both phases
    __shared__ float ldi[64][65];
    int wg = blockIdx.x;
    int bl = wg & nbm1;
    int rest = wg >> nbshift;
    int ft = rest & 63;            // 64 f-tiles
    int ct = rest >> 6;            // 4 c-tiles
    int f0 = ft << 6, c0 = ct << 6;
    int t = threadIdx.x;
    int cl = t & 63;
    int rq = t >> 6;               // 0..3
    const float scale = 1.0f / (4096.0f * 1.5f);
    int bg = b0 + bl;
    const float* xrb = xr + (size_t)bg * NF * NC;
    const float* xib = xi + (size_t)bg * NF * NC;
#pragma unroll
    for (int q = 0; q < 16; q++) {
        int r = q * 4 + rq;        // f-row in tile
        size_t idx = (size_t)(f0 + r) * NC + c0 + cl;   // consecutive cl -> coalesced
        ldr[cl][r] = xrb[idx] * scale;
        ldi[cl][r] = xib[idx] * scale;
    }
    __syncthreads();
    int fl = t & 63;
#pragma unroll
    for (int q = 0; q < 16; q++) {
        int cr = q * 4 + rq;       // c-row in tile
        fin[((size_t)(bl * NC + c0 + cr)) * NF + f0 + fl] =
            make_float2(ldr[cr][fl], ldi[cr][fl]);      // consecutive fl -> coalesced
    }
}

// ---------------- stage B: IFFT-4096 in place over fin[b,c,:], Stockham radix-16 ----------------
#define IPAD(a) ((a) + ((a) >> 4))

template<int P>
__device__ __forceinline__ void pass16(float2* S, int t, float sgn) {
    const int k = t & (P - 1);
    float2 u[16];
#pragma unroll
    for (int r = 0; r < 16; r++) u[r] = S[IPAD(t + 256 * r)];
    __syncthreads();
    if (P > 1) {
        float ab = sgn * (TWO_PI_F / (16.0f * (float)P)) * (float)k;
#pragma unroll
        for (int r = 1; r < 16; r++) {
            float sn, cs; __sincosf(ab * (float)r, &sn, &cs);
            u[r] = cmul(u[r], make_float2(cs, sn));
        }
    }
    dft16(u, sgn);
    const int base = 16 * P * (t / P) + k;
#pragma unroll
    for (int j = 0; j < 16; j++) {
        const int sl = ((j & 3) << 2) | (j >> 2);
        S[IPAD(base + j * P)] = u[sl];
    }
    __syncthreads();
}

__global__ __launch_bounds__(256) void ifft4096_kernel(float2* __restrict__ fin,
                                                       int bmask, int bshift) {
    __shared__ float2 S[4352];   // 34 KiB
    int wg = blockIdx.x;
    int bl = wg & bmask;
    int c = wg >> bshift;
    int t = threadIdx.x;
    size_t base = ((size_t)(bl * NC + c)) * NF;
    const float4* g4 = (const float4*)(fin + base);   // 16B-aligned (base multiple of 4096)
#pragma unroll
    for (int q = 0; q < 8; q++) {
        float4 v = g4[t + 256 * q];                   // coalesced 16B/lane
        int f = 2 * (t + 256 * q);
        S[IPAD(f)]     = make_float2(v.x, v.y);
        S[IPAD(f + 1)] = make_float2(v.z, v.w);
    }
    __syncthreads();
    pass16<1>(S, t, 1.0f);
    pass16<16>(S, t, 1.0f);
    pass16<256>(S, t, 1.0f);
    float4* o4 = (float4*)(fin + base);
#pragma unroll
    for (int q = 0; q < 8; q++) {
        int f = 2 * (t + 256 * q);
        float2 a = S[IPAD(f)];
        float2 b = S[IPAD(f + 1)];
        o4[t + 256 * q] = make_float4(a.x, a.y, b.x, b.y);
    }
}

// ---------------- stage C1: banded Gram, 2-k-per-thread, b128-LDS + fp64 accumulation ----------------
// fp64 accumulators make summation-order changes ~1e-15-relative -> restructuring is safe
// (f32 order changes are NOT: round-11 chaos amplification). Thread (kk 0..15, sg 0..15)
// owns k = k0+2kk, k0+2kk+1, all 8 d, m-strip 8*sg..8*sg+7. Adjacent k share 8/9 a-rows and
// k+1's d=1 a-row == k's b-row: 10 b128 loads per float4-step feed 128 f64 FMAs.
#define GST 142
__global__ __launch_bounds__(256) void gram_kernel(const float2* __restrict__ fin,
                                                   float2* __restrict__ gpart) {
    __shared__ float2 lfc[40 * GST];   // 44.4 KiB
    int wg = blockIdx.x;            // ((bl*8)+ks)*32 + ch
    int bl = wg >> 8;
    int ks = (wg >> 5) & 7;
    int ch = wg & 31;
    int m0 = ch * CH;
    int k0 = ks * 32;
    int t = threadIdx.x;
#pragma unroll
    for (int q = 0; q < 20; q++) {
        int e = t + 256 * q;
        int row = e >> 7;
        int m = e & 127;
        int gk = k0 - 8 + row;
        float2 v = (gk >= 0) ? fin[((size_t)(bl * NC + gk)) * NF + m0 + m]
                             : make_float2(0.f, 0.f);
        lfc[row * GST + 18 * (m >> 4) + (m & 15)] = v;
    }
    __syncthreads();
    int kk = t >> 4;                // 0..15 -> k = k0 + 2kk + {0,1}
    int sg = t & 15;                // 0..15 -> m-strip 8*sg..8*sg+7
    // strip base offset inside a row: m = 8*sg -> 18*(m>>4) + (m&15)
    int sbase = 18 * (sg >> 1) + 8 * (sg & 1);
    double a0x[8], a0y[8], a1x[8], a1y[8];
#pragma unroll
    for (int d = 0; d < 8; d++) { a0x[d] = 0.0; a0y[d] = 0.0; a1x[d] = 0.0; a1y[d] = 0.0; }
    const float2* rbase = &lfc[2 * kk * GST + sbase];    // row j at + j*GST
#pragma unroll
    for (int mm = 0; mm < 8; mm += 2) {
        float4 r[10];
#pragma unroll
        for (int j = 0; j < 10; j++)
            r[j] = *(const float4*)(rbase + j * GST + mm);
        float4 b0 = r[8];   // k = k0+2kk   (lds row 2kk+8)
        float4 b1 = r[9];   // k = k0+2kk+1 (lds row 2kk+9)
#pragma unroll
        for (int d = 1; d <= 8; d++) {
            float4 aa = r[8 - d];          // a-row for (k=2kk, d)
            a0x[d - 1] = fma((double)aa.y, (double)b0.y,
                         fma((double)aa.x, (double)b0.x, a0x[d - 1]));
            a0y[d - 1] = fma((double)aa.x, (double)b0.y,
                         fma(-(double)aa.y, (double)b0.x, a0y[d - 1]));
            a0x[d - 1] = fma((double)aa.w, (double)b0.w,
                         fma((double)aa.z, (double)b0.z, a0x[d - 1]));
            a0y[d - 1] = fma((double)aa.z, (double)b0.w,
                         fma(-(double)aa.w, (double)b0.z, a0y[d - 1]));
            float4 ab = r[9 - d];          // a-row for (k=2kk+1, d)
            a1x[d - 1] = fma((double)ab.y, (double)b1.y,
                         fma((double)ab.x, (double)b1.x, a1x[d - 1]));
            a1y[d - 1] = fma((double)ab.x, (double)b1.y,
                         fma(-(double)ab.y, (double)b1.x, a1y[d - 1]));
            a1x[d - 1] = fma((double)ab.w, (double)b1.w,
                         fma((double)ab.z, (double)b1.z, a1x[d - 1]));
            a1y[d - 1] = fma((double)ab.z, (double)b1.w,
                         fma(-(double)ab.w, (double)b1.z, a1y[d - 1]));
        }
    }
    // reduce over the 16 sg strips (xor on low 4 bits of t stays within kk group & wave)
    size_t gb0 = ((size_t)(bl * 32 + ch) * NC + (k0 + 2 * kk)) * 8;
#pragma unroll
    for (int d = 0; d < 8; d++) {
        double sx0 = a0x[d], sy0 = a0y[d], sx1 = a1x[d], sy1 = a1y[d];
#pragma unroll
        for (int off = 1; off <= 8; off <<= 1) {
            sx0 += __shfl_xor(sx0, off);
            sy0 += __shfl_xor(sy0, off);
            sx1 += __shfl_xor(sx1, off);
            sy1 += __shfl_xor(sy1, off);
        }
        if (sg == 0) {   // d>k entries stay exact zeros -> no poison downstream
            gpart[gb0 + d]     = make_float2((float)sx0, (float)sy0);
            gpart[gb0 + 8 + d] = make_float2((float)sx1, (float)sy1);
        }
    }
}

// ---------------- stage C2a: sum Gram partials over 32 chunks ----------------
__global__ void gsum_kernel(const float2* __restrict__ gpart, float2* __restrict__ gs, int total) {
    int e = blockIdx.x * blockDim.x + threadIdx.x;
    if (e >= total) return;
    int bl = e >> 11;
    int kd = e & 2047;
    float2 s = make_float2(0.f, 0.f);
    for (int ch = 0; ch < 32; ch++) {
        float2 v = gpart[((size_t)(bl * 32 + ch)) * 2048 + kd];
        s.x += v.x; s.y += v.y;
    }
    gs[e] = s;
}

// ---------------- stage C2b: scalar phase recurrence, deep (12-step) pinned prefetch ----------------
#define SCAN_STEP(A0, A1, A2, A3, KIDX)  do {                                  \
    float rx0 = p1.x*A0.x - p1.y*A0.y, ry0 = p1.x*A0.y + p1.y*A0.x;            \
    float rx1 = p2.x*A0.z - p2.y*A0.w, ry1 = p2.x*A0.w + p2.y*A0.z;            \
    float rx2 = p3.x*A1.x - p3.y*A1.y, ry2 = p3.x*A1.y + p3.y*A1.x;            \
    float rx3 = p4.x*A1.z - p4.y*A1.w, ry3 = p4.x*A1.w + p4.y*A1.z;            \
    float rx4 = p5.x*A2.x - p5.y*A2.y, ry4 = p5.x*A2.y + p5.y*A2.x;            \
    float rx5 = p6.x*A2.z - p6.y*A2.w, ry5 = p6.x*A2.w + p6.y*A2.z;            \
    float rx6 = p7.x*A3.x - p7.y*A3.y, ry6 = p7.x*A3.y + p7.y*A3.x;            \
    float rx7 = p8.x*A3.z - p8.y*A3.w, ry7 = p8.x*A3.w + p8.y*A3.z;            \
    float sx = ((rx0 + rx1) + (rx2 + rx3)) + ((rx4 + rx5) + (rx6 + rx7));      \
    float sy = ((ry0 + ry1) + (ry2 + ry3)) + ((ry4 + ry5) + (ry6 + ry7));      \
    float inv = rsqrtf(sx * sx + sy * sy);                                     \
    float2 np = make_float2(sx * inv, sy * inv);                               \
    phase[t * NC + (KIDX)] = np;                                               \
    p8 = p7; p7 = p6; p6 = p5; p5 = p4; p4 = p3; p3 = p2; p2 = p1; p1 = np;    \
} while (0)

#define SCAN_LOADG4(BUF, KBASE)  do {                                          \
    _Pragma("unroll") for (int j = 0; j < 4; j++) {                            \
        _Pragma("unroll") for (int q = 0; q < 4; q++)                          \
            BUF[j][q] = gb4[((KBASE) + j) * 4 + q];                            \
    }                                                                          \
} while (0)

#define SCAN_GRP4(BUF, KBASE, FIRST)  do {                                     \
    _Pragma("unroll") for (int j = 0; j < 4; j++) {                            \
        if (FIRST && j == 0) {                                                 \
            phase[t * NC] = make_float2(1.f, 0.f);                             \
        } else {                                                               \
            SCAN_STEP(BUF[j][0], BUF[j][1], BUF[j][2], BUF[j][3], (KBASE) + j);\
        }                                                                      \
    }                                                                          \
} while (0)

__global__ __launch_bounds__(64, 1) void scan_copy_kernel(const float2* __restrict__ gs,
                                                          float2* __restrict__ phase, int nb,
                                                          const float4* __restrict__ csrc,
                                                          float4* __restrict__ cdst, int cn4) {
    if (blockIdx.x != 0) {
        int i = (blockIdx.x - 1) * 64 + threadIdx.x;
        int stride = (gridDim.x - 1) * 64;
        for (; i < cn4; i += stride) cdst[i] = csrc[i];
        return;
    }
    int t = threadIdx.x;
    if (t >= nb) return;
    const float4* gb4 = (const float4*)(gs + (size_t)t * 2048);   // 256 rows x 4 float4
    float2 z = make_float2(0.f, 0.f);
    float2 p1 = make_float2(1.f, 0.f);
    float2 p2 = z, p3 = z, p4 = z, p5 = z, p6 = z, p7 = z, p8 = z;
    float4 B0[4][4], B1[4][4], B2[4][4], B3[4][4];
    SCAN_LOADG4(B0, 0);
    SCAN_LOADG4(B1, 4);
    SCAN_LOADG4(B2, 8);
    __builtin_amdgcn_sched_barrier(0);
    for (int i = 0; i < 16; i++) {
        int k0 = i * 16;
        SCAN_LOADG4(B3, k0 + 12);
        __builtin_amdgcn_sched_barrier(0);
        if (i == 0) { SCAN_GRP4(B0, k0, true); } else { SCAN_GRP4(B0, k0, false); }
        SCAN_LOADG4(B0, k0 + 16);          // prefetch-tail overrun (i=15) stays in d_ws
        __builtin_amdgcn_sched_barrier(0);
        SCAN_GRP4(B1, k0 + 4, false);
        SCAN_LOADG4(B1, k0 + 20);
        __builtin_amdgcn_sched_barrier(0);
        SCAN_GRP4(B2, k0 + 8, false);
        SCAN_LOADG4(B2, k0 + 24);
        __builtin_amdgcn_sched_barrier(0);
        SCAN_GRP4(B3, k0 + 12, false);
    }
}

// ---------------- stage C3 (fallback paths only): fin *= conj(phase) ----------------
__global__ void scale_kernel(float4* __restrict__ fin4, const float2* __restrict__ phase, int n4) {
    int i = blockIdx.x * blockDim.x + threadIdx.x;
    if (i >= n4) return;
    int row = i >> 11;
    float2 ph = phase[row];
    float4 v = fin4[i];
    fin4[i] = make_float4(v.x*ph.x + v.y*ph.y, v.y*ph.x - v.x*ph.y,
                          v.z*ph.x + v.w*ph.y, v.w*ph.x - v.z*ph.y);
}

// ---------------- stage D: FFT-512 over c (zero-padded), Stockham radix-8, fused conj(phase) ----------------
#define FPAD 516   // row stride (float2) for [8][516] LDS

template<int P, bool ZTOP>
__device__ __forceinline__ void pass8x(float2* L, int fp, int i2, float sgn) {
    const int ia = i2, ib = i2 + 32;
    const int ka = ia & (P - 1), kb = ib & (P - 1);
    float2 ua[8], ub[8];
#pragma unroll
    for (int r = 0; r < 8; r++) {
        if (ZTOP && r >= 4) {
            ua[r] = make_float2(0.f, 0.f);
            ub[r] = make_float2(0.f, 0.f);
        } else {
            ua[r] = L[fp * FPAD + ia + 64 * r];
            ub[r] = L[fp * FPAD + ib + 64 * r];
        }
    }
    __syncthreads();
    if (P > 1) {
        float aba = sgn * (TWO_PI_F / (8.0f * (float)P)) * (float)ka;
        float abb = sgn * (TWO_PI_F / (8.0f * (float)P)) * (float)kb;
#pragma unroll
        for (int r = 1; r < 8; r++) {
            float sn, cs;
            __sincosf(aba * (float)r, &sn, &cs);
            ua[r] = cmul(ua[r], make_float2(cs, sn));
            __sincosf(abb * (float)r, &sn, &cs);
            ub[r] = cmul(ub[r], make_float2(cs, sn));
        }
    }
    float2 va[8], vb[8];
    dft8(ua, va, sgn);
    dft8(ub, vb, sgn);
    const int basea = 8 * P * (ia / P) + ka;
    const int baseb = 8 * P * (ib / P) + kb;
#pragma unroll
    for (int r = 0; r < 8; r++) {
        L[fp * FPAD + basea + r * P] = va[r];
        L[fp * FPAD + baseb + r * P] = vb[r];
    }
    __syncthreads();
}

__global__ __launch_bounds__(256) void fft512_kernel(const float2* __restrict__ fin,
                                                     const float2* __restrict__ ph,   // may be null
                                                     float* __restrict__ outr,
                                                     float2* __restrict__ outc,
                                                     int b0, int realOnly) {
    __shared__ float2 L[8 * FPAD];   // 33 KiB
    int wg = blockIdx.x;             // bl*512 + ftile
    int bl = wg >> 9;
    int f0 = (wg & 511) * 8;
    int t = threadIdx.x;
    int fpp = t & 7;
    int cg = t >> 3;                 // 0..31
#pragma unroll
    for (int it = 0; it < 8; it++) {
        int c = it * 32 + cg;
        float2 v = fin[((size_t)(bl * NC + c)) * NF + f0 + fpp];
        if (ph) {
            float2 p = ph[bl * NC + c];
            v = make_float2(v.x * p.x + v.y * p.y, v.y * p.x - v.x * p.y);  // f*conj(ph)
        }
        L[fpp * FPAD + c] = v;
    }
    __syncthreads();
    int fp = t & 7;
    int i2 = t >> 3;                 // 0..31
    pass8x<1, true >(L, fp, i2, -1.0f);
    pass8x<8, false>(L, fp, i2, -1.0f);
    pass8x<64, false>(L, fp, i2, -1.0f);
    size_t ob = ((size_t)((b0 + bl) * NF + f0)) * NJ;
    if (realOnly) {
#pragma unroll
        for (int fp2 = 0; fp2 < 8; fp2++) {
            int j = 2 * t;           // thread covers j, j+1 -> 8B store, coalesced
            float2 w = make_float2(L[fp2 * FPAD + j].x, L[fp2 * FPAD + j + 1].x);
            *(float2*)&outr[ob + (size_t)fp2 * NJ + j] = w;
        }
    } else {
#pragma unroll
        for (int fp2 = 0; fp2 < 8; fp2++)
#pragma unroll
            for (int jq = 0; jq < 2; jq++) {
                int j = t + 256 * jq;
                outc[ob + (size_t)fp2 * NJ + j] = L[fp2 * FPAD + j];
            }
    }
}

// ---------------- output 0 writers (fallback paths) ----------------
__global__ void copy_kernel(const float4* __restrict__ src, float4* __restrict__ dst, int n4) {
    int i = blockIdx.x * blockDim.x + threadIdx.x;
    int stride = gridDim.x * blockDim.x;
    for (; i < n4; i += stride) dst[i] = src[i];
}
__global__ void pack_x_kernel(const float2* __restrict__ xr, const float2* __restrict__ xi,
                              float4* __restrict__ out, int n4) {
    int i = blockIdx.x * blockDim.x + threadIdx.x;
    int stride = gridDim.x * blockDim.x;
    for (; i < n4; i += stride) {
        float2 r = xr[i], m = xi[i];
        out[i] = make_float4(r.x, m.x, r.y, m.y);
    }
}

extern "C" void kernel_launch(void* const* d_in, const int* in_sizes, int n_in,
                              void* d_out, int out_size, void* d_ws, size_t ws_size,
                              hipStream_t stream) {
    const float* xr = (const float*)d_in[0];
    const float* xi = (const float*)d_in[1];
    float* out = (float*)d_out;

    if (out_size < 40000000) {
        // real-only outputs: out0 = x_real (8388608 f), out3 = Re(out3) (16777216 f)
        float* out0r = out;
        float* out3r = out + 8388608;
        size_t need = (size_t)(8388608 + 524288 + 16384 + 2048) * sizeof(float2);
        if (ws_size >= need) {
            float2* fin   = (float2*)d_ws;
            float2* gpart = fin + 8388608;
            float2* gsb   = gpart + 524288;
            float2* phase = gsb + 16384;
            transpose_kernel<<<8 * 256, 256, 0, stream>>>(xr, xi, fin, 0, 7, 3);
            ifft4096_kernel<<<8 * NC, 256, 0, stream>>>(fin, 7, 3);
            gram_kernel<<<8 * 256, 256, 0, stream>>>(fin, gpart);
            gsum_kernel<<<(8 * 2048) / 256, 256, 0, stream>>>(gpart, gsb, 8 * 2048);
            // block 0: serial scan; blocks 1..2048: out0 copy (independent, overlapped)
            scan_copy_kernel<<<2049, 64, 0, stream>>>(gsb, phase, 8,
                                                      (const float4*)xr, (float4*)out0r, 2097152);
            fft512_kernel<<<8 * 512, 256, 0, stream>>>(fin, phase, out3r, nullptr, 0, 1);
        } else {
            // two batch-half passes; fin in out0 region; gram scratch in out3 tail
            float2* fin   = (float2*)out0r;
            float2* o3f2  = (float2*)out3r;
            float2* gpart = o3f2 + (8388608 - 262144 - 8192 - 1024);
            float2* gsb   = o3f2 + (8388608 - 8192 - 1024);
            float2* phase = o3f2 + (8388608 - 1024);
            for (int p = 0; p < 2; p++) {
                int b0 = p * 4;
                transpose_kernel<<<4 * 256, 256, 0, stream>>>(xr, xi, fin, b0, 3, 2);
                ifft4096_kernel<<<4 * NC, 256, 0, stream>>>(fin, 3, 2);
                gram_kernel<<<4 * 256, 256, 0, stream>>>(fin, gpart);
                gsum_kernel<<<(4 * 2048) / 256, 256, 0, stream>>>(gpart, gsb, 4 * 2048);
                scan_copy_kernel<<<1, 64, 0, stream>>>(gsb, phase, 4, nullptr, nullptr, 0);
                scale_kernel<<<4 * 2048, 256, 0, stream>>>((float4*)fin, phase, 4 * 524288);
                fft512_kernel<<<4 * 512, 256, 0, stream>>>(fin, nullptr, out3r, nullptr, b0, 1);
            }
            copy_kernel<<<2048, 256, 0, stream>>>((const float4*)xr, (float4*)out0r, 2097152);
        }
    } else {
        // defensive path: complex outputs as float pairs
        float2* out0f2 = (float2*)out;
        float2* out3f2 = (float2*)(out + 16777216);
        float2* fin   = out0f2;
        float2* gpart = out3f2 + (16777216 - 524288 - 16384 - 2048);
        float2* gsb   = out3f2 + (16777216 - 16384 - 2048);
        float2* phase = out3f2 + (16777216 - 2048);
        transpose_kernel<<<8 * 256, 256, 0, stream>>>(xr, xi, fin, 0, 7, 3);
        ifft4096_kernel<<<8 * NC, 256, 0, stream>>>(fin, 7, 3);
        gram_kernel<<<8 * 256, 256, 0, stream>>>(fin, gpart);
        gsum_kernel<<<(8 * 2048) / 256, 256, 0, stream>>>(gpart, gsb, 8 * 2048);
        scan_copy_kernel<<<1, 64, 0, stream>>>(gsb, phase, 8, nullptr, nullptr, 0);
        scale_kernel<<<8 * 2048, 256, 0, stream>>>((float4*)fin, phase, 8 * 524288);
        fft512_kernel<<<8 * 512, 256, 0, stream>>>(fin, nullptr, nullptr, out3f2, 0, 0);
        pack_x_kernel<<<4096, 256, 0, stream>>>((const float2*)xr, (const float2*)xi,
                                                (float4*)out0f2, 4194304);
    }
}